// Round 1
// baseline (621.522 us; speedup 1.0000x reference)
//
#include <hip/hip_runtime.h>

#define NNODES 100000
#define DN 64
#define SROW 136   // act row stride in bf16 elems: 272B = 17*16B (aligned, 2-way banks)

typedef short bf16x8 __attribute__((ext_vector_type(8)));
typedef float f32x4 __attribute__((ext_vector_type(4)));

__device__ __forceinline__ unsigned short f2bf(float f) {
  unsigned int u = __float_as_uint(f);
  u = (u + 0x7fffu + ((u >> 16) & 1u)) >> 16;   // RNE
  return (unsigned short)u;
}
__device__ __forceinline__ float bf2f(unsigned short h) {
  return __uint_as_float(((unsigned int)h) << 16);
}

// ---------------------------------------------------------------------------
// Direct segment-sum via device-scope fp32 atomics. One wave per edge:
// lane c handles channel c. Read is one coalesced 256B wave-load; the atomic
// is one instruction covering 64 contiguous floats (4 cache lines) of the
// destination row. agg is 25.6MB -> resident in memory-side Infinity Cache,
// where device-scope atomics execute. Replaces hist/scan/fillconv/gather.
// ---------------------------------------------------------------------------
__global__ __launch_bounds__(256) void scatter_kernel(
    const int* __restrict__ col, const float* __restrict__ ea,
    float* __restrict__ agg, int n) {
  int t = blockIdx.x * 256 + threadIdx.x;
  int e = t >> 6;
  if (e >= n) return;
  int c = t & 63;
  int d = col[e];
  float v = ea[(size_t)e * 64 + c];
  atomicAdd(agg + (size_t)d * 64 + c, v);
}

// ---------------------------------------------------------------------------
// Weight prep: fp32 -> bf16 in exact MFMA B-fragment order.
// ---------------------------------------------------------------------------
__global__ __launch_bounds__(256) void wprep_kernel(
    const float* __restrict__ W0, const float* __restrict__ W1,
    const float* __restrict__ W2, unsigned short* __restrict__ wp) {
  int t = blockIdx.x * 256 + threadIdx.x;
  if (t >= 5120) return;
  const float* W; int c, N, dstbase;
  if (t < 2048)      { W = W0; c = t;        N = 128; dstbase = 0; }
  else if (t < 4096) { W = W1; c = t - 2048; N = 128; dstbase = 16384; }
  else               { W = W2; c = t - 4096; N = 64;  dstbase = 32768; }
  int blk = c >> 6;           // (nc*4+kc)
  int lane = c & 63;
  int nc = blk >> 2, kc = blk & 3;
  int k0 = kc * 32 + (lane >> 4) * 8;
  int n  = nc * 16 + (lane & 15);
  unsigned short* dst = wp + dstbase + blk * 512 + lane * 8;
#pragma unroll
  for (int j = 0; j < 8; ++j) dst[j] = f2bf(W[(size_t)(k0 + j) * N + n]);
}

// ---------------------------------------------------------------------------
// MLP(3 layers, bf16 MFMA) + LayerNorm + residual. One wave = 16 nodes.
// No __syncthreads: all LDS is wave-private.
// A-frag: A[m=lane&15][k=(lane>>4)*8+j]; B-frag preswizzled in wp;
// C/D: col=lane&15, row=(lane>>4)*4+reg.
// ---------------------------------------------------------------------------
__global__ __launch_bounds__(256) void fused_mlp(
    const float* __restrict__ x, const float* __restrict__ agg,
    const unsigned short* __restrict__ wp,
    const float* __restrict__ b0, const float* __restrict__ b1,
    const float* __restrict__ b2, const float* __restrict__ lng,
    const float* __restrict__ lnb, float* __restrict__ out) {
  __shared__ unsigned short act[4 * 2 * 16 * SROW];

  const int tid = threadIdx.x;
  const int wid = tid >> 6;
  const int lane = tid & 63;
  const int gw = blockIdx.x * 4 + wid;
  if (gw >= NNODES / 16) return;           // 6250 waves exactly
  const int base = gw * 16;
  const int m = lane & 15;
  const int quad = lane >> 4;

  unsigned short* Abuf = act + (wid * 2 + 0) * 16 * SROW;
  unsigned short* Bbuf = act + (wid * 2 + 1) * 16 * SROW;

  // ---- stage concat(x, agg) as bf16 into Abuf [16 x 128] ----
#pragma unroll 4
  for (int r = 0; r < 16; ++r) {
    int node = base + r;
    Abuf[r * SROW + lane] = f2bf(x[(size_t)node * 64 + lane]);
    Abuf[r * SROW + 64 + lane] = f2bf(agg[(size_t)node * 64 + lane]);
  }

  bf16x8 af[4];

  // ---- Layer 0: Abuf -> Bbuf, N=128, ReLU ----
#pragma unroll
  for (int kc = 0; kc < 4; ++kc)
    af[kc] = *(const bf16x8*)(Abuf + m * SROW + kc * 32 + quad * 8);
#pragma unroll
  for (int nc = 0; nc < 8; ++nc) {
    float bv = b0[nc * 16 + m];
    f32x4 acc = {bv, bv, bv, bv};
#pragma unroll
    for (int kc = 0; kc < 4; ++kc) {
      bf16x8 bf = *(const bf16x8*)(wp + (nc * 4 + kc) * 512 + lane * 8);
      acc = __builtin_amdgcn_mfma_f32_16x16x32_bf16(af[kc], bf, acc, 0, 0, 0);
    }
    int col = nc * 16 + m;
#pragma unroll
    for (int r2 = 0; r2 < 4; ++r2)
      Bbuf[(quad * 4 + r2) * SROW + col] = f2bf(fmaxf(acc[r2], 0.f));
  }

  // ---- Layer 1: Bbuf -> Abuf, N=128, ReLU ----
#pragma unroll
  for (int kc = 0; kc < 4; ++kc)
    af[kc] = *(const bf16x8*)(Bbuf + m * SROW + kc * 32 + quad * 8);
#pragma unroll
  for (int nc = 0; nc < 8; ++nc) {
    float bv = b1[nc * 16 + m];
    f32x4 acc = {bv, bv, bv, bv};
#pragma unroll
    for (int kc = 0; kc < 4; ++kc) {
      bf16x8 bf = *(const bf16x8*)(wp + 16384 + (nc * 4 + kc) * 512 + lane * 8);
      acc = __builtin_amdgcn_mfma_f32_16x16x32_bf16(af[kc], bf, acc, 0, 0, 0);
    }
    int col = nc * 16 + m;
#pragma unroll
    for (int r2 = 0; r2 < 4; ++r2)
      Abuf[(quad * 4 + r2) * SROW + col] = f2bf(fmaxf(acc[r2], 0.f));
  }

  // ---- Layer 2: Abuf -> registers, N=64, +b2 ----
#pragma unroll
  for (int kc = 0; kc < 4; ++kc)
    af[kc] = *(const bf16x8*)(Abuf + m * SROW + kc * 32 + quad * 8);
  f32x4 acc2[4];
#pragma unroll
  for (int nc = 0; nc < 4; ++nc) {
    float bv = b2[nc * 16 + m];
    f32x4 acc = {bv, bv, bv, bv};
#pragma unroll
    for (int kc = 0; kc < 4; ++kc) {
      bf16x8 bf = *(const bf16x8*)(wp + 32768 + (nc * 4 + kc) * 512 + lane * 8);
      acc = __builtin_amdgcn_mfma_f32_16x16x32_bf16(af[kc], bf, acc, 0, 0, 0);
    }
    acc2[nc] = acc;
  }

  // ---- LayerNorm(64) + residual; rows quad*4+r2, cols nc*16+m ----
  float s[4], ss[4];
#pragma unroll
  for (int r2 = 0; r2 < 4; ++r2) {
    float a0 = acc2[0][r2], a1 = acc2[1][r2], a2 = acc2[2][r2], a3 = acc2[3][r2];
    s[r2]  = a0 + a1 + a2 + a3;
    ss[r2] = a0 * a0 + a1 * a1 + a2 * a2 + a3 * a3;
  }
#pragma unroll
  for (int msk = 1; msk < 16; msk <<= 1) {
#pragma unroll
    for (int r2 = 0; r2 < 4; ++r2) {
      s[r2]  += __shfl_xor(s[r2], msk);
      ss[r2] += __shfl_xor(ss[r2], msk);
    }
  }
  float mu[4], rs[4];
#pragma unroll
  for (int r2 = 0; r2 < 4; ++r2) {
    mu[r2] = s[r2] * 0.015625f;
    float var = ss[r2] * 0.015625f - mu[r2] * mu[r2];
    rs[r2] = rsqrtf(var + 1e-5f);
  }
#pragma unroll
  for (int nc = 0; nc < 4; ++nc) {
    int col = nc * 16 + m;
    float g = lng[col], bb = lnb[col];
#pragma unroll
    for (int r2 = 0; r2 < 4; ++r2) {
      int node = base + quad * 4 + r2;
      float xr = x[(size_t)node * 64 + col];
      out[(size_t)node * 64 + col] =
          (acc2[nc][r2] - mu[r2]) * rs[r2] * g + bb + xr;
    }
  }
}

extern "C" void kernel_launch(void* const* d_in, const int* in_sizes, int n_in,
                              void* d_out, int out_size, void* d_ws, size_t ws_size,
                              hipStream_t stream) {
  const float* x  = (const float*)d_in[0];
  const int*   ei = (const int*)d_in[1];
  const float* ea = (const float*)d_in[2];
  const float* W0 = (const float*)d_in[3];
  const float* b0 = (const float*)d_in[4];
  const float* W1 = (const float*)d_in[5];
  const float* b1 = (const float*)d_in[6];
  const float* W2 = (const float*)d_in[7];
  const float* b2 = (const float*)d_in[8];
  const float* lg = (const float*)d_in[9];
  const float* lb = (const float*)d_in[10];
  float* out = (float*)d_out;

  const int n_edges = in_sizes[2] / DN;     // 1,200,000
  const int* col = ei + n_edges;            // edge_index[1]

  // ws layout (bytes)
  char* ws = (char*)d_ws;
  unsigned short* wp = (unsigned short*)(ws + 0);        // 40960 bf16 (80KB)
  float* agg = (float*)(ws + 81920);                     // 100000*64 f32 (25.6MB)

  hipMemsetAsync(agg, 0, (size_t)NNODES * DN * sizeof(float), stream);

  wprep_kernel<<<20, 256, 0, stream>>>(W0, W1, W2, wp);

  // one wave per edge: n_edges*64 threads
  scatter_kernel<<<(n_edges * 64 + 255) / 256, 256, 0, stream>>>(
      col, ea, agg, n_edges);

  int nblocks = (NNODES / 16 + 3) / 4;      // 1563
  fused_mlp<<<nblocks, 256, 0, stream>>>(x, agg, wp, b0, b1, b2, lg, lb, out);
}